// Round 8
// baseline (161.345 us; speedup 1.0000x reference)
//
#include <hip/hip_runtime.h>

#define BB   8
#define SS   4096
#define DD   64
#define NBB  32

typedef float f32x4 __attribute__((ext_vector_type(4)));
typedef short s16x8 __attribute__((ext_vector_type(8)));

#if defined(__has_builtin)
#if __has_builtin(__builtin_amdgcn_exp2f)
#define EXP2(x) __builtin_amdgcn_exp2f(x)
#else
#define EXP2(x) exp2f(x)
#endif
#else
#define EXP2(x) exp2f(x)
#endif

#define MFMA16(a, b, c) __builtin_amdgcn_mfma_f32_16x16x32_bf16((a), (b), (c), 0, 0, 0)

__device__ __forceinline__ unsigned short f2bf(float x) {
  unsigned u = __builtin_bit_cast(unsigned, x);
  u += 0x7fffu + ((u >> 16) & 1u);
  return (unsigned short)(u >> 16);
}

// packed f32x2 -> bf16x2 (RNE), single instruction
__device__ __forceinline__ unsigned cvtpk(float lo, float hi) {
  unsigned r;
  asm("v_cvt_pk_bf16_f32 %0, %1, %2" : "=v"(r) : "v"(lo), "v"(hi));
  return r;
}

// ---------------- prep (512 thr) ----------------
// K image (16KB/blk), LINEAR:  byte[row*128 + 2d] = bf16(K[row][d])
// V image (16KB/blk), h-permuted cols (so QK^T accumulator IS the PV B-frag):
//   kv = s*32+h*16+g*4+t  ->  byte[d*256 + 2*(s*32+g*8+h*4+t)] = bf16(V[kv][d])
__global__ __launch_bounds__(512) void bsattn_prep(
    const float* __restrict__ kp, const float* __restrict__ vp,
    char* __restrict__ kimg, char* __restrict__ vimg) {
  __shared__ float vt[128 * 68];  // fp32 V tile (row kv, col d), padded
  const int tid = threadIdx.x;
  const int blk = blockIdx.x;  // b*NBB + kb
  const float* kbp = kp + (size_t)blk * 128 * DD;
  const float* vbp = vp + (size_t)blk * 128 * DD;
  char* kdst = kimg + ((size_t)blk << 14);
  char* vdst = vimg + ((size_t)blk << 14);
  const int drow = tid & 15, rr = tid >> 4;  // rr 0..31
#pragma unroll
  for (int p = 0; p < 4; ++p) {
    int row = p * 32 + rr;
    float4 kx = *(const float4*)(kbp + row * DD + drow * 4);
    ushort4 k4;
    k4.x = f2bf(kx.x); k4.y = f2bf(kx.y); k4.z = f2bf(kx.z); k4.w = f2bf(kx.w);
    *(ushort4*)(kdst + row * 128 + drow * 8) = k4;
    float4 vx = *(const float4*)(vbp + row * DD + drow * 4);
    *(float4*)(&vt[row * 68 + drow * 4]) = vx;
  }
  __syncthreads();
  const int l5 = tid & 31, dtop = tid >> 5;  // dtop 0..15
  const int kv0 = l5 * 4;  // s=l5>>3, h=(l5>>2)&1, g=l5&3, t=0..3
  const int c0b = ((l5 >> 3) * 64) + ((l5 & 3) * 16) + (((l5 >> 2) & 1) * 8);
#pragma unroll
  for (int p = 0; p < 4; ++p) {
    int d = p * 16 + dtop;
    ushort4 v4;
    v4.x = f2bf(vt[(kv0 + 0) * 68 + d]);
    v4.y = f2bf(vt[(kv0 + 1) * 68 + d]);
    v4.z = f2bf(vt[(kv0 + 2) * 68 + d]);
    v4.w = f2bf(vt[(kv0 + 3) * 68 + d]);
    *(ushort4*)(vdst + d * 256 + c0b) = v4;
  }
}

// ---------------- main ----------------
// Grid 512 = (b:8) x (qb:32) x (half:2).  WG = 64 q rows, 8 waves = wq:2 x wk:4;
// wave owns 32q x 32kv.  NO LDS staging, NO main-loop barriers: MFMA A-fragments
// are loaded straight from the (L2-resident, per-XCD) K/V images into VGPRs.
// Swapped MFMA; in-register softmax (deferred cross-lane sum, defer-max);
// PV B-frag = cvt_pk'd QK accumulator via the V-image k-permutation.
__global__ __launch_bounds__(512, 4) void bsattn_main(
    const float* __restrict__ qp, const int* __restrict__ layout,
    const char* __restrict__ kimg, const char* __restrict__ vimg,
    float* __restrict__ out) {
  __shared__ float Opub[2][3][32][68];  // per-wq publish buffers (padded)
  __shared__ float Ml[2][2][3][32];     // per-wq m/l

  const int tid = threadIdx.x, lane = tid & 63, wid = tid >> 6;
  const int wq = wid >> 2, wk = wid & 3;
  const int l16 = lane & 15, lg = lane >> 4;

  const int bidx = blockIdx.x;
  const int b = bidx & 7;       // one batch per XCD -> images L2-resident
  const int idx = bidx >> 3;
  const int hf = idx & 1, qb = idx >> 1;
  const int q0 = qb * 128 + hf * 64 + wq * 32;

  // live-block bitmask (wave-uniform scalar)
  unsigned long long mask =
      __ballot((lane < 32) && (layout[qb * NBB + lane] != 0));
  const int nlive = __popcll(mask);
  unsigned long long rem = mask;

  // Q fragments (B-operand: col q=l16, k=d), pre-scaled by log2(e)/sqrt(D)
  const float qscale = 0.18033688011112042f;
  s16x8 qf[2][2];
  {
    const float* qbase = qp + ((size_t)b * SS + q0) * DD;
#pragma unroll
    for (int qc = 0; qc < 2; ++qc) {
      const float* qrow = qbase + (qc * 16 + l16) * DD;
#pragma unroll
      for (int kc = 0; kc < 2; ++kc) {
        const float* p0 = qrow + kc * 32 + lg * 8;
        float4 x = *(const float4*)(p0);
        float4 y = *(const float4*)(p0 + 4);
        s16x8 f;
        f[0] = (short)f2bf(x.x * qscale); f[1] = (short)f2bf(x.y * qscale);
        f[2] = (short)f2bf(x.z * qscale); f[3] = (short)f2bf(x.w * qscale);
        f[4] = (short)f2bf(y.x * qscale); f[5] = (short)f2bf(y.y * qscale);
        f[6] = (short)f2bf(y.z * qscale); f[7] = (short)f2bf(y.w * qscale);
        qf[qc][kc] = f;
      }
    }
  }

  f32x4 o_acc[2][4];
  float mreg[2], psum[2];
#pragma unroll
  for (int qc = 0; qc < 2; ++qc) {
    mreg[qc] = -INFINITY;
    psum[qc] = 0.0f;
#pragma unroll
    for (int dch = 0; dch < 4; ++dch) o_acc[qc][dch] = (f32x4)(0.0f);
  }

  // per-lane constant byte offsets within a 16KB image block
  const int kbase = (wk * 32 + l16) * 128 + lg * 16;  // + kvc*2048 + kc*64
  const int vbase = l16 * 256 + wk * 64 + lg * 16;    // + dch*4096
  const char* imgK = kimg + ((size_t)(b * NBB) << 14);
  const char* imgV = vimg + ((size_t)(b * NBB) << 14);

  for (int i = 0; i < nlive; ++i) {
    const int kb = (int)__builtin_ctzll(rem);
    rem &= rem - 1;
    const char* kblk = imgK + ((size_t)kb << 14);
    const char* vblk = imgV + ((size_t)kb << 14);

    // ---- fragment loads (8 independent 16B loads, all in flight) ----
    s16x8 ak[2][2], av[4];
#pragma unroll
    for (int kvc = 0; kvc < 2; ++kvc)
#pragma unroll
      for (int kc = 0; kc < 2; ++kc)
        ak[kvc][kc] = *(const s16x8*)(kblk + kbase + kvc * 2048 + kc * 64);
#pragma unroll
    for (int dch = 0; dch < 4; ++dch)
      av[dch] = *(const s16x8*)(vblk + vbase + dch * 4096);

    // ---- QK^T (S^T: rows kv, cols q=l16); ak shared by both q-tiles ----
    f32x4 sc[2][2];
#pragma unroll
    for (int qc = 0; qc < 2; ++qc)
#pragma unroll
      for (int kvc = 0; kvc < 2; ++kvc) sc[qc][kvc] = (f32x4)(0.0f);
    __builtin_amdgcn_s_setprio(1);
#pragma unroll
    for (int kvc = 0; kvc < 2; ++kvc)
#pragma unroll
      for (int kc = 0; kc < 2; ++kc) {
        sc[0][kvc] = MFMA16(ak[kvc][kc], qf[0][kc], sc[0][kvc]);
        sc[1][kvc] = MFMA16(ak[kvc][kc], qf[1][kc], sc[1][kvc]);
      }
    __builtin_amdgcn_s_setprio(0);

    // ---- online softmax per q-tile (lane q=l16; kv = wk*32+kvc*16+lg*4+r) ----
    s16x8 pf[2];
#pragma unroll
    for (int qc = 0; qc < 2; ++qc) {
      float mx = fmaxf(fmaxf(fmaxf(sc[qc][0][0], sc[qc][0][1]),
                             fmaxf(sc[qc][0][2], sc[qc][0][3])),
                       fmaxf(fmaxf(sc[qc][1][0], sc[qc][1][1]),
                             fmaxf(sc[qc][1][2], sc[qc][1][3])));
      mx = fmaxf(mx, __shfl_xor(mx, 16));
      mx = fmaxf(mx, __shfl_xor(mx, 32));
      // defer-max (T13): only rescale when the running max grew by > 5 (log2)
      if (!__all(mx - mreg[qc] <= 5.0f)) {
        float mn = fmaxf(mreg[qc], mx);
        float al = EXP2(mreg[qc] - mn);
        mreg[qc] = mn;
        psum[qc] *= al;
#pragma unroll
        for (int dch = 0; dch < 4; ++dch) o_acc[qc][dch] *= al;
      }
      const float mn = mreg[qc];
#pragma unroll
      for (int kvc = 0; kvc < 2; ++kvc)
#pragma unroll
        for (int r = 0; r < 4; ++r) {
          float e = EXP2(sc[qc][kvc][r] - mn);
          sc[qc][kvc][r] = e;
          psum[qc] += e;
        }
      // pack P^T fragment: u16[j] = P[kv = wk*32 + (j>>2)*16 + lg*4 + (j&3)]
      int4 pk;
      pk.x = (int)cvtpk(sc[qc][0][0], sc[qc][0][1]);
      pk.y = (int)cvtpk(sc[qc][0][2], sc[qc][0][3]);
      pk.z = (int)cvtpk(sc[qc][1][0], sc[qc][1][1]);
      pk.w = (int)cvtpk(sc[qc][1][2], sc[qc][1][3]);
      pf[qc] = __builtin_bit_cast(s16x8, pk);
    }

    // ---- PV (O^T += V^T * P^T); av shared by both q-tiles ----
    __builtin_amdgcn_s_setprio(1);
#pragma unroll
    for (int dch = 0; dch < 4; ++dch) {
      o_acc[0][dch] = MFMA16(av[dch], pf[0], o_acc[0][dch]);
      o_acc[1][dch] = MFMA16(av[dch], pf[1], o_acc[1][dch]);
    }
    __builtin_amdgcn_s_setprio(0);
  }

  // finalize deferred sums
  float lreg[2];
#pragma unroll
  for (int qc = 0; qc < 2; ++qc) {
    float s = psum[qc];
    s += __shfl_xor(s, 16);
    s += __shfl_xor(s, 32);
    lreg[qc] = s;
  }

  // ---- merge 4 kv quarters per wq-group: wk=1..3 publish, wk=0 merges ----
  if (wk != 0) {
#pragma unroll
    for (int qc = 0; qc < 2; ++qc) {
      const int ql = qc * 16 + l16;
      float* orow = Opub[wq][wk - 1][ql];
#pragma unroll
      for (int dch = 0; dch < 4; ++dch)
        *(f32x4*)(&orow[dch * 16 + lg * 4]) = o_acc[qc][dch];
      if (lg == 0) {
        Ml[wq][0][wk - 1][ql] = mreg[qc];
        Ml[wq][1][wk - 1][ql] = lreg[qc];
      }
    }
  }
  __syncthreads();
  if (wk == 0) {
#pragma unroll
    for (int qc = 0; qc < 2; ++qc) {
      const int ql = qc * 16 + l16;
      float m1 = Ml[wq][0][0][ql], m2 = Ml[wq][0][1][ql], m3 = Ml[wq][0][2][ql];
      float l1 = Ml[wq][1][0][ql], l2 = Ml[wq][1][1][ql], l3 = Ml[wq][1][2][ql];
      float mm = fmaxf(fmaxf(mreg[qc], m1), fmaxf(m2, m3));
      float a0 = EXP2(mreg[qc] - mm), a1 = EXP2(m1 - mm);
      float a2 = EXP2(m2 - mm), a3 = EXP2(m3 - mm);
      float inv = 1.0f / (lreg[qc] * a0 + l1 * a1 + l2 * a2 + l3 * a3);
      float* gout = out + ((size_t)b * SS + q0 + ql) * DD;
#pragma unroll
      for (int dch = 0; dch < 4; ++dch) {
        const int co = dch * 16 + lg * 4;
        f32x4 o1 = *(const f32x4*)(&Opub[wq][0][ql][co]);
        f32x4 o2 = *(const f32x4*)(&Opub[wq][1][ql][co]);
        f32x4 o3 = *(const f32x4*)(&Opub[wq][2][ql][co]);
        f32x4 r = (o_acc[qc][dch] * a0 + o1 * a1 + o2 * a2 + o3 * a3) * inv;
        *(f32x4*)(gout + co) = r;
      }
    }
  }
}

extern "C" void kernel_launch(void* const* d_in, const int* in_sizes, int n_in,
                              void* d_out, int out_size, void* d_ws, size_t ws_size,
                              hipStream_t stream) {
  (void)in_sizes; (void)n_in; (void)out_size; (void)ws_size;
  const float* q = (const float*)d_in[0];
  const float* k = (const float*)d_in[1];
  const float* v = (const float*)d_in[2];
  const int* layout = (const int*)d_in[3];
  float* out = (float*)d_out;
  char* kimg = (char*)d_ws;               // 4 MB
  char* vimg = (char*)d_ws + (4u << 20);  // 4 MB
  bsattn_prep<<<dim3(BB * NBB), dim3(512), 0, stream>>>(k, v, kimg, vimg);
  bsattn_main<<<dim3(512), dim3(512), 0, stream>>>(q, layout, kimg, vimg, out);
}

// Round 12
// 118.704 us; speedup vs baseline: 1.3592x; 1.3592x over previous
//
#include <hip/hip_runtime.h>

#define BB   8
#define SS   4096
#define DD   64
#define NBB  32

typedef float f32x4 __attribute__((ext_vector_type(4)));
typedef short s16x8 __attribute__((ext_vector_type(8)));

#if defined(__has_builtin)
#if __has_builtin(__builtin_amdgcn_exp2f)
#define EXP2(x) __builtin_amdgcn_exp2f(x)
#else
#define EXP2(x) exp2f(x)
#endif
#else
#define EXP2(x) exp2f(x)
#endif

#define MFMA16(a, b, c) __builtin_amdgcn_mfma_f32_16x16x32_bf16((a), (b), (c), 0, 0, 0)

__device__ __forceinline__ unsigned short f2bf(float x) {
  unsigned u = __builtin_bit_cast(unsigned, x);
  u += 0x7fffu + ((u >> 16) & 1u);
  return (unsigned short)(u >> 16);
}

// packed f32x2 -> bf16x2 (RNE), single instruction
__device__ __forceinline__ unsigned cvtpk(float lo, float hi) {
  unsigned r;
  asm("v_cvt_pk_bf16_f32 %0, %1, %2" : "=v"(r) : "v"(lo), "v"(hi));
  return r;
}

__device__ __forceinline__ void gl_lds16(const void* g, void* l) {
  __builtin_amdgcn_global_load_lds(
      (const __attribute__((address_space(1))) unsigned int*)g,
      (__attribute__((address_space(3))) unsigned int*)l, 16, 0, 0);
}

// ---------------- prep (512 thr) ----------------
// K image (16KB/blk): byte[row*128 + ((2d) ^ ((row&7)<<4))] = bf16(K[row][d])
// V image (16KB/blk): kv = s*32+h*16+g*4+t -> byte[d*256 + ((s*64+g*16+h*8+2t) ^ ((d&7)<<4))]
//   (h-permuted columns so the QK^T accumulator IS the PV B-fragment)
__global__ __launch_bounds__(512) void bsattn_prep(
    const float* __restrict__ kp, const float* __restrict__ vp,
    char* __restrict__ kimg, char* __restrict__ vimg) {
  __shared__ float vt[128 * 68];  // fp32 V tile (row kv, col d), padded
  const int tid = threadIdx.x;
  const int blk = blockIdx.x;  // b*NBB + kb
  const float* kbp = kp + (size_t)blk * 128 * DD;
  const float* vbp = vp + (size_t)blk * 128 * DD;
  char* kdst = kimg + ((size_t)blk << 14);
  char* vdst = vimg + ((size_t)blk << 14);
  const int drow = tid & 15, rr = tid >> 4;  // rr 0..31
#pragma unroll
  for (int p = 0; p < 4; ++p) {
    int row = p * 32 + rr;
    float4 kx = *(const float4*)(kbp + row * DD + drow * 4);
    ushort4 k4;
    k4.x = f2bf(kx.x); k4.y = f2bf(kx.y); k4.z = f2bf(kx.z); k4.w = f2bf(kx.w);
    *(ushort4*)(kdst + row * 128 + ((drow * 8) ^ ((row & 7) << 4))) = k4;
    float4 vx = *(const float4*)(vbp + row * DD + drow * 4);
    *(float4*)(&vt[row * 68 + drow * 4]) = vx;
  }
  __syncthreads();
  const int l5 = tid & 31, dtop = tid >> 5;  // dtop 0..15
  const int kv0 = l5 * 4;  // s=l5>>3, h=(l5>>2)&1, g=l5&3, t=0..3
  const int c0b = ((l5 >> 3) * 64) + ((l5 & 3) * 16) + (((l5 >> 2) & 1) * 8);
#pragma unroll
  for (int p = 0; p < 4; ++p) {
    int d = p * 16 + dtop;
    ushort4 v4;
    v4.x = f2bf(vt[(kv0 + 0) * 68 + d]);
    v4.y = f2bf(vt[(kv0 + 1) * 68 + d]);
    v4.z = f2bf(vt[(kv0 + 2) * 68 + d]);
    v4.w = f2bf(vt[(kv0 + 3) * 68 + d]);
    *(ushort4*)(vdst + d * 256 + (c0b ^ ((d & 7) << 4))) = v4;
  }
}

// ---------------- main ----------------
// Grid 512 = (b:8) x (qb:32) x (half:2).  WG = 64 q rows, 8 waves = wq:2 (32q,
// two 16-row MFMA tiles) x wk:4 (32kv).  Double-buffered 2x32KB LDS staging
// (stage-at-top, one vmcnt(0)+barrier per iter).  Swapped MFMA; in-register
// softmax (deferred cross-lane sum, defer-max); PV B-frag = cvt_pk'd QK
// accumulator via the V-image k-permutation; ak/av fragments shared across
// the wave's two q-tiles (halves LDS fragment traffic vs 16q waves).
__global__ __launch_bounds__(512, 4) void bsattn_main(
    const float* __restrict__ qp, const int* __restrict__ layout,
    const char* __restrict__ kimg, const char* __restrict__ vimg,
    float* __restrict__ out) {
  __shared__ alignas(16) char smem[65536];  // buf b: K at b*32768, V^T at +16384

  const int tid = threadIdx.x, lane = tid & 63, wid = tid >> 6;
  const int wq = wid >> 2, wk = wid & 3;
  const int l16 = lane & 15, lg = lane >> 4;
  const int l7 = l16 & 7;

  const int bidx = blockIdx.x;
  const int b = bidx & 7;       // one batch per XCD
  const int idx = bidx >> 3;    // 0..63
  const int hf = idx & 1, qb = idx >> 1;
  const int q0 = qb * 128 + hf * 64 + wq * 32;  // this wave's 32-q base

  // live-block bitmask (wave-uniform scalar)
  unsigned long long mask =
      __ballot((lane < 32) && (layout[qb * NBB + lane] != 0));
  const int nlive = __popcll(mask);
  unsigned long long rem = mask;

  // Q fragments (B-operand: col q=l16, k=d), pre-scaled by log2(e)/sqrt(D)
  const float qscale = 0.18033688011112042f;
  s16x8 qf[2][2];
  {
    const float* qbase = qp + ((size_t)b * SS + q0) * DD;
#pragma unroll
    for (int qc = 0; qc < 2; ++qc) {
      const float* qrow = qbase + (qc * 16 + l16) * DD;
#pragma unroll
      for (int kc = 0; kc < 2; ++kc) {
        const float* p0 = qrow + kc * 32 + lg * 8;
        float4 x = *(const float4*)(p0);
        float4 y = *(const float4*)(p0 + 4);
        s16x8 f;
        f[0] = (short)f2bf(x.x * qscale); f[1] = (short)f2bf(x.y * qscale);
        f[2] = (short)f2bf(x.z * qscale); f[3] = (short)f2bf(x.w * qscale);
        f[4] = (short)f2bf(y.x * qscale); f[5] = (short)f2bf(y.y * qscale);
        f[6] = (short)f2bf(y.z * qscale); f[7] = (short)f2bf(y.w * qscale);
        qf[qc][kc] = f;
      }
    }
  }

  f32x4 o_acc[2][4];
  float mreg[2], psum[2];
#pragma unroll
  for (int qc = 0; qc < 2; ++qc) {
    mreg[qc] = -INFINITY;
    psum[qc] = 0.0f;
#pragma unroll
    for (int dch = 0; dch < 4; ++dch) o_acc[qc][dch] = (f32x4)(0.0f);
  }

  const size_t imgbase = ((size_t)(b * NBB) << 14);
  const int st_g = wid * 2048 + lane * 16;  // global src offset (per-lane)
  const int st_l = wid * 2048;              // LDS dst offset (wave-uniform)

#define STAGE(bufsel, kbv)                                              \
  do {                                                                  \
    const char* ks_ = kimg + imgbase + ((size_t)(kbv) << 14) + st_g;    \
    const char* vs_ = vimg + imgbase + ((size_t)(kbv) << 14) + st_g;    \
    char* kd_ = smem + (bufsel) * 32768 + st_l;                         \
    char* vd_ = smem + (bufsel) * 32768 + 16384 + st_l;                 \
    _Pragma("unroll")                                                   \
    for (int i_ = 0; i_ < 2; ++i_) {                                    \
      gl_lds16(ks_ + i_ * 1024, kd_ + i_ * 1024);                       \
      gl_lds16(vs_ + i_ * 1024, vd_ + i_ * 1024);                       \
    }                                                                   \
  } while (0)

  // prologue: stage first live block
  {
    int kb0 = (int)__builtin_ctzll(rem);
    rem &= rem - 1;
    STAGE(0, kb0);
  }
  asm volatile("s_waitcnt vmcnt(0)" ::: "memory");
  __syncthreads();

  int buf = 0;
  for (int i = 0; i < nlive; ++i) {
    if (i + 1 < nlive) {  // wave-uniform; writes the buffer read at iter i-1
      int kbn = (int)__builtin_ctzll(rem);
      rem &= rem - 1;
      STAGE(buf ^ 1, kbn);
    }
    const char* Kb = smem + buf * 32768;
    const char* Vb = Kb + 16384;

    // ---- QK^T (S^T: rows kv, cols q=l16); ak shared by both q-tiles ----
    f32x4 sc[2][2];
#pragma unroll
    for (int qc = 0; qc < 2; ++qc)
#pragma unroll
      for (int kvc = 0; kvc < 2; ++kvc) sc[qc][kvc] = (f32x4)(0.0f);
    __builtin_amdgcn_s_setprio(1);
#pragma unroll
    for (int kvc = 0; kvc < 2; ++kvc) {
      const char* kr = Kb + (wk * 32 + kvc * 16 + l16) * 128;
#pragma unroll
      for (int kc = 0; kc < 2; ++kc) {
        s16x8 ak = *(const s16x8*)(kr + (((kc * 4 + lg) ^ l7) << 4));
        sc[0][kvc] = MFMA16(ak, qf[0][kc], sc[0][kvc]);
        sc[1][kvc] = MFMA16(ak, qf[1][kc], sc[1][kvc]);
      }
    }
    __builtin_amdgcn_s_setprio(0);

    // ---- online softmax per q-tile (lane q=l16; kv = wk*32+kvc*16+lg*4+r) ----
    s16x8 pf[2];
#pragma unroll
    for (int qc = 0; qc < 2; ++qc) {
      float mx = fmaxf(fmaxf(fmaxf(sc[qc][0][0], sc[qc][0][1]),
                             fmaxf(sc[qc][0][2], sc[qc][0][3])),
                       fmaxf(fmaxf(sc[qc][1][0], sc[qc][1][1]),
                             fmaxf(sc[qc][1][2], sc[qc][1][3])));
      mx = fmaxf(mx, __shfl_xor(mx, 16));
      mx = fmaxf(mx, __shfl_xor(mx, 32));
      // defer-max (T13): only rescale when the running max grew by > 5 (log2)
      if (!__all(mx - mreg[qc] <= 5.0f)) {
        float mn = fmaxf(mreg[qc], mx);
        float al = EXP2(mreg[qc] - mn);
        mreg[qc] = mn;
        psum[qc] *= al;
#pragma unroll
        for (int dch = 0; dch < 4; ++dch) o_acc[qc][dch] *= al;
      }
      const float mn = mreg[qc];
#pragma unroll
      for (int kvc = 0; kvc < 2; ++kvc)
#pragma unroll
        for (int r = 0; r < 4; ++r) {
          float e = EXP2(sc[qc][kvc][r] - mn);
          sc[qc][kvc][r] = e;
          psum[qc] += e;
        }
      // pack P^T fragment: u16[j] = P[kv = wk*32 + (j>>2)*16 + lg*4 + (j&3)]
      int4 pk;
      pk.x = (int)cvtpk(sc[qc][0][0], sc[qc][0][1]);
      pk.y = (int)cvtpk(sc[qc][0][2], sc[qc][0][3]);
      pk.z = (int)cvtpk(sc[qc][1][0], sc[qc][1][1]);
      pk.w = (int)cvtpk(sc[qc][1][2], sc[qc][1][3]);
      pf[qc] = __builtin_bit_cast(s16x8, pk);
    }

    // ---- PV (O^T += V^T * P^T); av shared by both q-tiles ----
    __builtin_amdgcn_s_setprio(1);
    const int colb = (((wk * 4 + lg) ^ l7) << 4);
#pragma unroll
    for (int dch = 0; dch < 4; ++dch) {
      s16x8 av = *(const s16x8*)(Vb + (dch * 16 + l16) * 256 + colb);
      o_acc[0][dch] = MFMA16(av, pf[0], o_acc[0][dch]);
      o_acc[1][dch] = MFMA16(av, pf[1], o_acc[1][dch]);
    }
    __builtin_amdgcn_s_setprio(0);

    asm volatile("s_waitcnt vmcnt(0)" ::: "memory");  // next-block stage landed
    __syncthreads();
    buf ^= 1;
  }

  // finalize deferred sums
  float lreg[2];
#pragma unroll
  for (int qc = 0; qc < 2; ++qc) {
    float s = psum[qc];
    s += __shfl_xor(s, 16);
    s += __shfl_xor(s, 32);
    lreg[qc] = s;
  }

  // ---- merge 4 kv quarters per wq-group (aliases staging LDS) ----
  float (*Opub)[3][32][68] = (float (*)[3][32][68])smem;          // 52224 B
  float (*Ml)[2][3][32] = (float (*)[2][3][32])(smem + 52224);    // 1536 B
  if (wk != 0) {
#pragma unroll
    for (int qc = 0; qc < 2; ++qc) {
      const int ql = qc * 16 + l16;
      float* orow = Opub[wq][wk - 1][ql];
#pragma unroll
      for (int dch = 0; dch < 4; ++dch)
        *(f32x4*)(&orow[dch * 16 + lg * 4]) = o_acc[qc][dch];
      if (lg == 0) {
        Ml[wq][0][wk - 1][ql] = mreg[qc];
        Ml[wq][1][wk - 1][ql] = lreg[qc];
      }
    }
  }
  __syncthreads();
  if (wk == 0) {
#pragma unroll
    for (int qc = 0; qc < 2; ++qc) {
      const int ql = qc * 16 + l16;
      float m1 = Ml[wq][0][0][ql], m2 = Ml[wq][0][1][ql], m3 = Ml[wq][0][2][ql];
      float l1 = Ml[wq][1][0][ql], l2 = Ml[wq][1][1][ql], l3 = Ml[wq][1][2][ql];
      float mm = fmaxf(fmaxf(mreg[qc], m1), fmaxf(m2, m3));
      float a0 = EXP2(mreg[qc] - mm), a1 = EXP2(m1 - mm);
      float a2 = EXP2(m2 - mm), a3 = EXP2(m3 - mm);
      float inv = 1.0f / (lreg[qc] * a0 + l1 * a1 + l2 * a2 + l3 * a3);
      float* gout = out + ((size_t)b * SS + q0 + ql) * DD;
#pragma unroll
      for (int dch = 0; dch < 4; ++dch) {
        const int co = dch * 16 + lg * 4;
        f32x4 o1 = *(const f32x4*)(&Opub[wq][0][ql][co]);
        f32x4 o2 = *(const f32x4*)(&Opub[wq][1][ql][co]);
        f32x4 o3 = *(const f32x4*)(&Opub[wq][2][ql][co]);
        f32x4 r = (o_acc[qc][dch] * a0 + o1 * a1 + o2 * a2 + o3 * a3) * inv;
        *(f32x4*)(gout + co) = r;
      }
    }
  }
#undef STAGE
}

extern "C" void kernel_launch(void* const* d_in, const int* in_sizes, int n_in,
                              void* d_out, int out_size, void* d_ws, size_t ws_size,
                              hipStream_t stream) {
  (void)in_sizes; (void)n_in; (void)out_size; (void)ws_size;
  const float* q = (const float*)d_in[0];
  const float* k = (const float*)d_in[1];
  const float* v = (const float*)d_in[2];
  const int* layout = (const int*)d_in[3];
  float* out = (float*)d_out;
  char* kimg = (char*)d_ws;               // 4 MB
  char* vimg = (char*)d_ws + (4u << 20);  // 4 MB
  bsattn_prep<<<dim3(BB * NBB), dim3(512), 0, stream>>>(k, v, kimg, vimg);
  bsattn_main<<<dim3(512), dim3(512), 0, stream>>>(q, layout, kimg, vimg, out);
}